// Round 6
// baseline (488.972 us; speedup 1.0000x reference)
//
#include <hip/hip_runtime.h>
#include <math.h>

// CRF forward-score scan, faithful to the reference's quirky log_sum_exp
// (max subtracted inside exp indexed by j, max added back indexed by i).
//
// Per-step factorization in BASE-2 units (x2 == x * log2e):
//   M2_i   = max_j(fv2_j + tr2_ij)
//   h_j    = exp2(fv2_j - M2_j - feat2_j)      [local to row-group j]
//   fv2'_i = M2_i + 2*feat2_i + log2(sum_j exp(tr_ij) * h_j)
// Verified on HW r5: passed, absmax 0.0.
//
// r5 measurement: 177.5 us = 832 cyc/step, VALUBusy 9% -> ~720 cyc/step of
// barrier+LDS+trans latency STALL (fixed cost per step, independent of how
// many chains a block carries). This round: interleave KSEQ=4 independent
// sequences per block so the fixed stall amortizes 4x; per-lane VALU per seq
// is only ~90 cyc so total issue stays ~450 cyc/step.
//
// 32 blocks x 192 thr (3 waves). Lane map: i = tid>>2 (row), jsub = tid&3
// owns j in [12*jsub, 12*jsub+12). tr2/E=exp(tr) row-slices in VGPRs, shared
// by all 4 seqs. fv2_i per seq carried in-register. 2 lgkmcnt-only barriers
// per step (floor for multi-wave: M and dot are global-over-j reduces).
// Features: global_load_lds direct to LDS (no staging VGPRs), issued at
// sl==0 for chunk c+1, published by vmcnt(0)+barrier at sl==CHUNK-2 -> 30
// steps of slack. CHUNK=32 keeps LDS at 50.7 KB (< 64 KB static limit).
//
// Hazard audit (gload writes featbuf[s][buf^1] at sl==0): buf^1's last
// readers ran in chunk c-1 (fbb reads through sl==30's featN, fbn read at
// sl==31); every wave drains its ds reads at each barrier (lgkmcnt(0)) and
// the issuing wave is >=2 barriers past those reads -> WAR safe. First read
// of the new data is featN at sl==31 (fbn) resp. next chunk's fbb reads,
// both after the per-wave vmcnt(0) at sl==30 + barrier B -> RAW safe.

#define TT 48
#define BB 128
#define SS 512
#define STARTI 46
#define ENDI 47
#define MINV 0.0001f
#define KSEQ 4
#define NBLK (BB / KSEQ)      // 32
#define CHUNK 32
#define NCHUNK (SS / CHUNK)   // 16
#define KPT 2                 // float4 gloads per thread per chunk (CHUNK*TT/4/192)
#define LOG2E 1.44269504088896340736f
#define LN2   0.69314718055994530942f

#if __has_builtin(__builtin_amdgcn_exp2f)
#define EXP2F(x) __builtin_amdgcn_exp2f(x)
#else
#define EXP2F(x) exp2f(x)
#endif
#if __has_builtin(__builtin_amdgcn_logf)   // v_log_f32: log base 2
#define LOG2F(x) __builtin_amdgcn_logf(x)
#else
#define LOG2F(x) log2f(x)
#endif

// quad_perm DPP: cross-lane within each aligned 4-lane group, VALU pipe.
// 0xB1 = [1,0,3,2] (xor 1), 0x4E = [2,3,0,1] (xor 2).
template <int CTRL>
__device__ __forceinline__ float qperm_f(float x) {
#if __has_builtin(__builtin_amdgcn_update_dpp)
    return __int_as_float(__builtin_amdgcn_update_dpp(
        0, __float_as_int(x), CTRL, 0xF, 0xF, true));
#elif __has_builtin(__builtin_amdgcn_mov_dpp)
    return __int_as_float(
        __builtin_amdgcn_mov_dpp(__float_as_int(x), CTRL, 0xF, 0xF, true));
#else
    return __shfl_xor(x, (CTRL == 0xB1) ? 1 : 2, 64);
#endif
}

// Block barrier making LDS ops visible (lgkmcnt(0) covers ds_read AND
// ds_write -> RAW and WAR both safe) without draining global vmcnt, so the
// async feature loads stay in flight across barriers.
__device__ __forceinline__ void sync_lds() {
    asm volatile("s_waitcnt lgkmcnt(0)" ::: "memory");
    __builtin_amdgcn_s_barrier();
    asm volatile("" ::: "memory");
}

#if __has_builtin(__builtin_amdgcn_global_load_lds)
#define HAVE_GLOAD 1
// 16B per lane, global -> LDS. lds base must be wave-uniform; global addr is
// per-lane. Writes lds[base + lane*16B].
__device__ __forceinline__ void gload16(const float* g, float* l) {
    __builtin_amdgcn_global_load_lds(
        (const __attribute__((address_space(1))) void*)g,
        (__attribute__((address_space(3))) void*)l, 16, 0, 0);
}
#else
#define HAVE_GLOAD 0
#endif

__global__ __launch_bounds__(192, 1) void crf_forward_kernel(
    const float* __restrict__ feats,   // [B, S, T]
    const float* __restrict__ trans,   // [T, T]
    float* __restrict__ out)           // [B]
{
    const int tid  = threadIdx.x;      // 0..191
    const int i    = tid >> 2;         // 0..47
    const int jsub = tid & 3;          // 0..3
    const int j0   = jsub * 12;
    const int wv   = tid >> 6;         // wave 0..2
    const int b0   = blockIdx.x * KSEQ;

    __shared__ __align__(16) float fv2[KSEQ][TT];
    __shared__ __align__(16) float hbuf[KSEQ][TT];
    __shared__ __align__(16) float featbuf[KSEQ][2][CHUNK * TT];  // 4*2*6KB

    // trans row-slice (same for all seqs): tr2 = tr*log2e, E = exp(tr).
    float tr2[12], E[12];
#pragma unroll
    for (int q = 0; q < 3; ++q) {
        float4 v = *reinterpret_cast<const float4*>(trans + i * TT + j0 + 4 * q);
        tr2[4 * q + 0] = v.x * LOG2E; tr2[4 * q + 1] = v.y * LOG2E;
        tr2[4 * q + 2] = v.z * LOG2E; tr2[4 * q + 3] = v.w * LOG2E;
    }
#pragma unroll
    for (int q = 0; q < 12; ++q) E[q] = EXP2F(tr2[q]);

    const float* fb[KSEQ];
#pragma unroll
    for (int s = 0; s < KSEQ; ++s)
        fb[s] = feats + (size_t)(b0 + s) * SS * TT;

    // Preload chunk 0 for all seqs.
#if HAVE_GLOAD
#pragma unroll
    for (int s = 0; s < KSEQ; ++s)
#pragma unroll
        for (int k = 0; k < KPT; ++k)
            gload16(fb[s] + k * 768 + tid * 4,
                    &featbuf[s][0][k * 768 + wv * 256]);
    asm volatile("s_waitcnt vmcnt(0)" ::: "memory");
#else
#pragma unroll
    for (int s = 0; s < KSEQ; ++s)
#pragma unroll
        for (int k = 0; k < KPT; ++k)
            *reinterpret_cast<float4*>(&featbuf[s][0][k * 768 + tid * 4]) =
                *reinterpret_cast<const float4*>(fb[s] + k * 768 + tid * 4);
#endif

    // fv2_0: MINV*log2e everywhere except 0 at START.
    if (tid < TT) {
#pragma unroll
        for (int s = 0; s < KSEQ; ++s)
            fv2[s][tid] = (tid == STARTI) ? 0.0f : (MINV * LOG2E);
    }
    sync_lds();

    float fv2i[KSEQ], feat2[KSEQ];
#pragma unroll
    for (int s = 0; s < KSEQ; ++s) {
        fv2i[s]  = (i == STARTI) ? 0.0f : (MINV * LOG2E);
        feat2[s] = featbuf[s][0][i] * LOG2E;
    }

    for (int c = 0; c < NCHUNK; ++c) {
        const int buf = c & 1;
        const bool hp = (c + 1 < NCHUNK);

        for (int sl = 0; sl < CHUNK; ++sl) {
            // Issue next chunk's async loads once per chunk (30 steps slack).
            if (sl == 0 && hp) {
#if HAVE_GLOAD
#pragma unroll
                for (int s = 0; s < KSEQ; ++s)
#pragma unroll
                    for (int k = 0; k < KPT; ++k)
                        gload16(fb[s] + (c + 1) * (CHUNK * TT) + k * 768 + tid * 4,
                                &featbuf[s][buf ^ 1][k * 768 + wv * 256]);
#else
#pragma unroll
                for (int s = 0; s < KSEQ; ++s)
#pragma unroll
                    for (int k = 0; k < KPT; ++k)
                        *reinterpret_cast<float4*>(&featbuf[s][buf ^ 1][k * 768 + tid * 4]) =
                            *reinterpret_cast<const float4*>(
                                fb[s] + (c + 1) * (CHUNK * TT) + k * 768 + tid * 4);
#endif
            }

            // ---- pass 1 (all seqs): issue all LDS reads first ----
            float4 va[KSEQ][3];
#pragma unroll
            for (int s = 0; s < KSEQ; ++s)
#pragma unroll
                for (int q = 0; q < 3; ++q)
                    va[s][q] = *reinterpret_cast<const float4*>(&fv2[s][j0 + 4 * q]);
            float featN[KSEQ];
#pragma unroll
            for (int s = 0; s < KSEQ; ++s)
                featN[s] = (sl + 1 < CHUNK) ? featbuf[s][buf][(sl + 1) * TT + i]
                                            : featbuf[s][buf ^ 1][i];

            float hs[KSEQ], qv2[KSEQ];
#pragma unroll
            for (int s = 0; s < KSEQ; ++s) {
                float a[12];
                a[0]  = va[s][0].x + tr2[0];  a[1]  = va[s][0].y + tr2[1];
                a[2]  = va[s][0].z + tr2[2];  a[3]  = va[s][0].w + tr2[3];
                a[4]  = va[s][1].x + tr2[4];  a[5]  = va[s][1].y + tr2[5];
                a[6]  = va[s][1].z + tr2[6];  a[7]  = va[s][1].w + tr2[7];
                a[8]  = va[s][2].x + tr2[8];  a[9]  = va[s][2].y + tr2[9];
                a[10] = va[s][2].z + tr2[10]; a[11] = va[s][2].w + tr2[11];
                float m0 = fmaxf(fmaxf(a[0], a[1]),  a[2]);
                float m1 = fmaxf(fmaxf(a[3], a[4]),  a[5]);
                float m2 = fmaxf(fmaxf(a[6], a[7]),  a[8]);
                float m3 = fmaxf(fmaxf(a[9], a[10]), a[11]);
                float M2 = fmaxf(fmaxf(fmaxf(m0, m1), m2), m3);
                M2 = fmaxf(M2, qperm_f<0xB1>(M2));
                M2 = fmaxf(M2, qperm_f<0x4E>(M2));
                hs[s]  = EXP2F((fv2i[s] - feat2[s]) - M2);
                qv2[s] = M2 + 2.0f * feat2[s];
            }
            if (jsub == 0) {
#pragma unroll
                for (int s = 0; s < KSEQ; ++s) hbuf[s][i] = hs[s];
            }
            sync_lds();   // (A) hbuf visible; all fv2 reads of this step done

            // ---- pass 2 (all seqs) ----
            float4 vh[KSEQ][3];
#pragma unroll
            for (int s = 0; s < KSEQ; ++s)
#pragma unroll
                for (int q = 0; q < 3; ++q)
                    vh[s][q] = *reinterpret_cast<const float4*>(&hbuf[s][j0 + 4 * q]);

            float nfv[KSEQ];
#pragma unroll
            for (int s = 0; s < KSEQ; ++s) {
                float d0 = E[0] * vh[s][0].x, d1 = E[1] * vh[s][0].y;
                float d2 = E[2] * vh[s][0].z, d3 = E[3] * vh[s][0].w;
                d0 = fmaf(E[4],  vh[s][1].x, d0); d1 = fmaf(E[5],  vh[s][1].y, d1);
                d2 = fmaf(E[6],  vh[s][1].z, d2); d3 = fmaf(E[7],  vh[s][1].w, d3);
                d0 = fmaf(E[8],  vh[s][2].x, d0); d1 = fmaf(E[9],  vh[s][2].y, d1);
                d2 = fmaf(E[10], vh[s][2].z, d2); d3 = fmaf(E[11], vh[s][2].w, d3);
                float dot = (d0 + d1) + (d2 + d3);
                dot += qperm_f<0xB1>(dot);
                dot += qperm_f<0x4E>(dot);
                nfv[s]   = qv2[s] + LOG2F(dot);
                fv2i[s]  = nfv[s];
                feat2[s] = featN[s] * LOG2E;
            }
            if (jsub == 0) {
#pragma unroll
                for (int s = 0; s < KSEQ; ++s) fv2[s][i] = nfv[s];
            }
#if HAVE_GLOAD
            // Publish next chunk's features: every wave waits its own async
            // loads, then barrier B makes them globally visible.
            if (sl == CHUNK - 2)
                asm volatile("s_waitcnt vmcnt(0)" ::: "memory");
#endif
            sync_lds();   // (B) new fv2 ready; hbuf reads all done
        }
    }

    // ---- terminal per seq: out = LSE_j( fv_j + trans[END][j] ), wave 0 ----
    if (tid < 64) {
        const float* te = trans + ENDI * TT;
#pragma unroll
        for (int s = 0; s < KSEQ; ++s) {
            float sc = (tid < TT) ? fmaf(fv2[s][tid], LN2, te[tid]) : -3.4e38f;
            float m = sc;
#pragma unroll
            for (int off = 32; off >= 1; off >>= 1)
                m = fmaxf(m, __shfl_xor(m, off));
            float e = (tid < TT) ? __expf(sc - m) : 0.0f;
#pragma unroll
            for (int off = 32; off >= 1; off >>= 1)
                e += __shfl_xor(e, off);
            if (tid == 0) out[b0 + s] = m + __logf(e);
        }
    }
}

extern "C" void kernel_launch(void* const* d_in, const int* in_sizes, int n_in,
                              void* d_out, int out_size, void* d_ws, size_t ws_size,
                              hipStream_t stream) {
    (void)in_sizes; (void)n_in; (void)out_size; (void)d_ws; (void)ws_size;
    const float* feats = (const float*)d_in[0];   // [128, 512, 48] f32
    const float* trans = (const float*)d_in[1];   // [48, 48] f32
    float* out = (float*)d_out;                   // [128] f32
    crf_forward_kernel<<<dim3(NBLK), dim3(192), 0, stream>>>(feats, trans, out);
}

// Round 8
// 258.175 us; speedup vs baseline: 1.8940x; 1.8940x over previous
//
#include <hip/hip_runtime.h>
#include <math.h>

// CRF forward-score scan, faithful to the reference's quirky log_sum_exp.
// Base-2 factorization (HW-verified r5/r6, absmax 0.0):
//   M2_i   = max_j(fv2_j + tr2_ij)
//   h_j    = exp2(fv2_j - M2_j - feat2_j)
//   fv2'_i = M2_i + 2*feat2_i + log2(sum_j exp(tr_ij) * h_j)
//
// r6 lesson (measured): LDS pipe is shared per CU and in r6's KSEQ=4 the
// redundant quad reads saturated it (2038 cyc/step). r5's 3-wave version:
// 832 cyc/step ~= chain(~400) + 2 barriers(~400). This round removes the
// barriers entirely: ONE WAVE per sequence (128 blocks x 64 thr).
// (r7 bench died to an infra "container failed twice" -- resubmitting the
// audited, unchanged kernel for a clean measurement.)
//  - wave-synchronous LDS: DS pipe is in-order per wave -> write->read needs
//    no barrier, no s_waitcnt beyond what the compiler inserts for reg deps.
//  - lane = i16*4+jsub; quad-split: jsub owns j in [12*jsub,12*jsub+12);
//    row-iterations r=0,1,2 cover rows i16, i16+16, i16+32 (16x4x3 = 48x4).
//  - fv slice (3x ds_read_b128) read ONCE per step, reused by all 3 rows;
//    same for h slice. ~14 DS instr/step on a private LDS pipe.
//  - per-step chain: read fv -> add/max3 tree -> exp2 -> write h -> read h
//    -> FMA tree -> log2 -> write fv  (~350-400 cyc; issue ~210 hides under)
// Features: global_load_lds direct to LDS, double-buffered 32-step chunks,
// issued at sl==0 for chunk c+1, vmcnt(0) at sl==30 (~30 steps of slack).

#define TT 48
#define BB 128
#define SS 512
#define STARTI 46
#define ENDI 47
#define MINV 0.0001f
#define CHUNK 32
#define NCHUNK (SS / CHUNK)   // 16
#define GPT 6                 // gload16 instrs per chunk: 32*48*4B / (64*16B)
#define LOG2E 1.44269504088896340736f
#define LN2   0.69314718055994530942f

#if __has_builtin(__builtin_amdgcn_exp2f)
#define EXP2F(x) __builtin_amdgcn_exp2f(x)
#else
#define EXP2F(x) exp2f(x)
#endif
#if __has_builtin(__builtin_amdgcn_logf)   // v_log_f32: log base 2
#define LOG2F(x) __builtin_amdgcn_logf(x)
#else
#define LOG2F(x) log2f(x)
#endif

// quad_perm DPP: cross-lane within each aligned 4-lane group, VALU pipe.
// 0xB1 = [1,0,3,2] (xor 1), 0x4E = [2,3,0,1] (xor 2).
template <int CTRL>
__device__ __forceinline__ float qperm_f(float x) {
#if __has_builtin(__builtin_amdgcn_update_dpp)
    return __int_as_float(__builtin_amdgcn_update_dpp(
        0, __float_as_int(x), CTRL, 0xF, 0xF, true));
#elif __has_builtin(__builtin_amdgcn_mov_dpp)
    return __int_as_float(
        __builtin_amdgcn_mov_dpp(__float_as_int(x), CTRL, 0xF, 0xF, true));
#else
    return __shfl_xor(x, (CTRL == 0xB1) ? 1 : 2, 64);
#endif
}

#if __has_builtin(__builtin_amdgcn_global_load_lds)
#define HAVE_GLOAD 1
// One instr: all 64 lanes move 16B each, global -> LDS[base + lane*16].
__device__ __forceinline__ void gload16(const float* g, float* l) {
    __builtin_amdgcn_global_load_lds(
        (const __attribute__((address_space(1))) void*)g,
        (__attribute__((address_space(3))) void*)l, 16, 0, 0);
}
#else
#define HAVE_GLOAD 0
#endif

__global__ __launch_bounds__(64, 1) void crf_forward_kernel(
    const float* __restrict__ feats,   // [B, S, T]
    const float* __restrict__ trans,   // [T, T]
    float* __restrict__ out)           // [B]
{
    const int lane = threadIdx.x;      // 0..63
    const int i16  = lane >> 2;        // 0..15
    const int jsub = lane & 3;         // 0..3
    const int j0   = jsub * 12;
    const int b    = blockIdx.x;

    __shared__ __align__(16) float fvb[TT];
    __shared__ __align__(16) float hb[TT];
    __shared__ __align__(16) float featbuf[2][CHUNK * TT];   // 2 x 6 KB

    // Per-lane slices for rows i16+16r: tr2 = tr*log2e, E = exp(tr).
    float tr2[3][12], E[3][12];
#pragma unroll
    for (int r = 0; r < 3; ++r) {
#pragma unroll
        for (int q = 0; q < 3; ++q) {
            float4 v = *reinterpret_cast<const float4*>(
                trans + (i16 + 16 * r) * TT + j0 + 4 * q);
            tr2[r][4 * q + 0] = v.x * LOG2E; tr2[r][4 * q + 1] = v.y * LOG2E;
            tr2[r][4 * q + 2] = v.z * LOG2E; tr2[r][4 * q + 3] = v.w * LOG2E;
        }
#pragma unroll
        for (int q = 0; q < 12; ++q) E[r][q] = EXP2F(tr2[r][q]);
    }

    const float* fb = feats + (size_t)b * SS * TT;

    // Preload chunk 0.
#if HAVE_GLOAD
#pragma unroll
    for (int k = 0; k < GPT; ++k)
        gload16(fb + k * 256 + lane * 4, &featbuf[0][k * 256]);
#else
#pragma unroll
    for (int k = 0; k < GPT; ++k)
        *reinterpret_cast<float4*>(&featbuf[0][k * 256 + lane * 4]) =
            *reinterpret_cast<const float4*>(fb + k * 256 + lane * 4);
#endif

    // fv2_0 in LDS and per-row registers.
    if (lane < TT) fvb[lane] = (lane == STARTI) ? 0.0f : (MINV * LOG2E);
    float fvi[3];
#pragma unroll
    for (int r = 0; r < 3; ++r)
        fvi[r] = ((i16 + 16 * r) == STARTI) ? 0.0f : (MINV * LOG2E);

#if HAVE_GLOAD
    asm volatile("s_waitcnt vmcnt(0)" ::: "memory");
#endif

    for (int c = 0; c < NCHUNK; ++c) {
        const int buf = c & 1;
        const bool hp = (c + 1 < NCHUNK);
        if (hp) {
#if HAVE_GLOAD
#pragma unroll
            for (int k = 0; k < GPT; ++k)
                gload16(fb + (c + 1) * (CHUNK * TT) + k * 256 + lane * 4,
                        &featbuf[buf ^ 1][k * 256]);
#else
#pragma unroll
            for (int k = 0; k < GPT; ++k)
                *reinterpret_cast<float4*>(&featbuf[buf ^ 1][k * 256 + lane * 4]) =
                    *reinterpret_cast<const float4*>(
                        fb + (c + 1) * (CHUNK * TT) + k * 256 + lane * 4);
#endif
        }

        for (int sl = 0; sl < CHUNK; ++sl) {
            // Feats for this lane's 3 rows (quad-broadcast reads, issue early).
            float feat2[3];
#pragma unroll
            for (int r = 0; r < 3; ++r)
                feat2[r] = featbuf[buf][sl * TT + i16 + 16 * r] * LOG2E;

            // fv slice: read ONCE, reused by all 3 row-iterations.
            float4 v0 = *reinterpret_cast<const float4*>(&fvb[j0]);
            float4 v1 = *reinterpret_cast<const float4*>(&fvb[j0 + 4]);
            float4 v2 = *reinterpret_cast<const float4*>(&fvb[j0 + 8]);
            float fvs[12] = {v0.x, v0.y, v0.z, v0.w, v1.x, v1.y,
                             v1.z, v1.w, v2.x, v2.y, v2.z, v2.w};

            float hs[3], qv2[3];
#pragma unroll
            for (int r = 0; r < 3; ++r) {
                float a[12];
#pragma unroll
                for (int q = 0; q < 12; ++q) a[q] = fvs[q] + tr2[r][q];
                float m0 = fmaxf(fmaxf(a[0], a[1]),  a[2]);
                float m1 = fmaxf(fmaxf(a[3], a[4]),  a[5]);
                float m2 = fmaxf(fmaxf(a[6], a[7]),  a[8]);
                float m3 = fmaxf(fmaxf(a[9], a[10]), a[11]);
                float M2 = fmaxf(fmaxf(fmaxf(m0, m1), m2), m3);
                M2 = fmaxf(M2, qperm_f<0xB1>(M2));
                M2 = fmaxf(M2, qperm_f<0x4E>(M2));
                hs[r]  = EXP2F((fvi[r] - feat2[r]) - M2);
                qv2[r] = M2 + 2.0f * feat2[r];
            }
            if (jsub == 0) {
                hb[i16]      = hs[0];
                hb[i16 + 16] = hs[1];
                hb[i16 + 32] = hs[2];
            }
            // Wave-synchronous: DS pipe in-order per wave -> reads below see
            // the writes above; compiler inserts the lgkmcnt for reg deps.
            float4 h0 = *reinterpret_cast<const float4*>(&hb[j0]);
            float4 h1 = *reinterpret_cast<const float4*>(&hb[j0 + 4]);
            float4 h2 = *reinterpret_cast<const float4*>(&hb[j0 + 8]);
            float hv[12] = {h0.x, h0.y, h0.z, h0.w, h1.x, h1.y,
                            h1.z, h1.w, h2.x, h2.y, h2.z, h2.w};

            float nfv[3];
#pragma unroll
            for (int r = 0; r < 3; ++r) {
                float d0 = E[r][0] * hv[0], d1 = E[r][1] * hv[1];
                float d2 = E[r][2] * hv[2], d3 = E[r][3] * hv[3];
                d0 = fmaf(E[r][4],  hv[4],  d0); d1 = fmaf(E[r][5],  hv[5],  d1);
                d2 = fmaf(E[r][6],  hv[6],  d2); d3 = fmaf(E[r][7],  hv[7],  d3);
                d0 = fmaf(E[r][8],  hv[8],  d0); d1 = fmaf(E[r][9],  hv[9],  d1);
                d2 = fmaf(E[r][10], hv[10], d2); d3 = fmaf(E[r][11], hv[11], d3);
                float dot = (d0 + d1) + (d2 + d3);
                dot += qperm_f<0xB1>(dot);
                dot += qperm_f<0x4E>(dot);
                nfv[r] = qv2[r] + LOG2F(dot);
                fvi[r] = nfv[r];
            }
            if (jsub == 0) {
                fvb[i16]      = nfv[0];
                fvb[i16 + 16] = nfv[1];
                fvb[i16 + 32] = nfv[2];
            }
#if HAVE_GLOAD
            if (sl == CHUNK - 2 && hp)
                asm volatile("s_waitcnt vmcnt(0)" ::: "memory");
#endif
        }
    }

    // ---- terminal: out[b] = LSE_j( fv_j + trans[END][j] ) ----
    // All lanes compute redundantly from the (in-order visible) final fvb.
    {
        const float* te = trans + ENDI * TT;
        float sc[TT];
#pragma unroll
        for (int q = 0; q < 12; ++q) {
            float4 fv4 = *reinterpret_cast<const float4*>(&fvb[4 * q]);
            float4 te4 = *reinterpret_cast<const float4*>(te + 4 * q);
            sc[4 * q + 0] = fmaf(fv4.x, LN2, te4.x);
            sc[4 * q + 1] = fmaf(fv4.y, LN2, te4.y);
            sc[4 * q + 2] = fmaf(fv4.z, LN2, te4.z);
            sc[4 * q + 3] = fmaf(fv4.w, LN2, te4.w);
        }
        float m = sc[0];
#pragma unroll
        for (int j = 1; j < TT; ++j) m = fmaxf(m, sc[j]);
        float s = 0.0f;
#pragma unroll
        for (int j = 0; j < TT; ++j) s += __expf(sc[j] - m);
        if (lane == 0) out[b] = m + __logf(s);
    }
}

extern "C" void kernel_launch(void* const* d_in, const int* in_sizes, int n_in,
                              void* d_out, int out_size, void* d_ws, size_t ws_size,
                              hipStream_t stream) {
    (void)in_sizes; (void)n_in; (void)out_size; (void)d_ws; (void)ws_size;
    const float* feats = (const float*)d_in[0];   // [128, 512, 48] f32
    const float* trans = (const float*)d_in[1];   // [48, 48] f32
    float* out = (float*)d_out;                   // [128] f32
    crf_forward_kernel<<<dim3(BB), dim3(64), 0, stream>>>(feats, trans, out);
}